// Round 15
// baseline (925.384 us; speedup 1.0000x reference)
//
#include <hip/hip_runtime.h>
#include <math.h>

#define BB 256
#define NEL 90
#define NMAX 270
#define C1 448
#define C2 256
#define PIN 448
#define LATH 128
#define SGE 64
#define P1 512
#define EPSB 1e-5f

typedef short shortx8 __attribute__((ext_vector_type(8)));
typedef float floatx4 __attribute__((ext_vector_type(4)));

__device__ __forceinline__ float bf2f(unsigned short u) {
  return __uint_as_float(((unsigned)u) << 16);
}
__device__ __forceinline__ unsigned short f2bf(float f) {
  unsigned x = __float_as_uint(f);
  unsigned r = (x + 0x7fffu + ((x >> 16) & 1u)) >> 16;
  return (unsigned short)r;
}
// async 16B global->LDS (gfx950). LDS dest: wave-uniform base + lane*16.
__device__ __forceinline__ void gld16(const void* g, void* l) {
  __builtin_amdgcn_global_load_lds(
      (const __attribute__((address_space(1))) unsigned int*)g,
      (__attribute__((address_space(3))) unsigned int*)l, 16, 0, 0);
}

// ================= mega prologue: prep | scan | physpe | wprep x2 | fold x2 | pad
#define NB_PREP  BB
#define NB_SCAN  1
#define NB_PHYS  NEL
#define NB_WP1   (14 * 42)
#define NB_WP2   (14 * 24)
#define NB_FOLD  112
#define NB_PAD   64
#define SETUP_GRID (NB_PREP + NB_SCAN + NB_PHYS + NB_WP1 + NB_WP2 + 2 * NB_FOLD + NB_PAD)

__global__ __launch_bounds__(256) void k_setup(
    const int* __restrict__ comp, const int* __restrict__ sg, const float* __restrict__ lat,
    const float* __restrict__ sg_emb,
    const float* __restrict__ lW1, const float* __restrict__ lb1,
    const float* __restrict__ lg1, const float* __restrict__ lbe1,
    const float* __restrict__ lm1, const float* __restrict__ lv1,
    const float* __restrict__ lW2, const float* __restrict__ lb2,
    const float* __restrict__ lg2, const float* __restrict__ lbe2,
    const float* __restrict__ lm2, const float* __restrict__ lv2,
    const int* __restrict__ period_idx, const int* __restrict__ group_idx,
    const float* __restrict__ z_emb, const float* __restrict__ period_t,
    const float* __restrict__ group_t, const float* __restrict__ props,
    const float* __restrict__ Wp, const float* __restrict__ bp,
    const float* __restrict__ Wphys, const float* __restrict__ bphys,
    const float* __restrict__ gat1_W, const float* __restrict__ gat1_as,
    const float* __restrict__ gat1_ad, const float* __restrict__ gat1_b,
    const float* __restrict__ gat2_W, const float* __restrict__ gat2_as,
    const float* __restrict__ gat2_ad, const float* __restrict__ gat2_b,
    float* __restrict__ sgx, float* __restrict__ latx, int* __restrict__ z,
    int* __restrict__ natoms, int* __restrict__ off, int* __restrict__ aoff,
    float* __restrict__ zerobuf, float* __restrict__ physpe,
    unsigned short* __restrict__ wt1, unsigned short* __restrict__ wt2,
    float* __restrict__ wsv1, float* __restrict__ wdv1,
    float* __restrict__ wsv2, float* __restrict__ wdv2, float* __restrict__ pad2) {
  int r = blockIdx.x;
  int tid = threadIdx.x;
  int wv = tid >> 6, lane = tid & 63;

  if (r < NB_PREP) {  // ---- prep (z, sgx, latx) ----
    int b = r;
    __shared__ int cum[NEL];
    __shared__ float hbuf[LATH];
    __shared__ float latl[6];
    if (tid == 0) {
      int s = 0;
      for (int e = 0; e < NEL; ++e) { s += comp[b * NEL + e]; cum[e] = s; }
    }
    if (tid < 6) latl[tid] = lat[b * 6 + tid];
    __syncthreads();
    int n = cum[NEL - 1];
    for (int t = tid; t < NMAX; t += 256) {
      int zz = -1;
      if (t < n) {
        for (int e = 0; e < NEL; ++e) { if (cum[e] > t) { zz = e; break; } }
      }
      z[b * NMAX + t] = zz;
    }
    if (tid < SGE) sgx[b * SGE + tid] = sg_emb[sg[b] * SGE + tid];
    if (tid < LATH) {
      float acc = lb1[tid];
      for (int k = 0; k < 6; ++k) acc += latl[k] * lW1[k * LATH + tid];
      acc = (acc - lm1[tid]) * lg1[tid] * rsqrtf(lv1[tid] + EPSB) + lbe1[tid];
      hbuf[tid] = acc;
    }
    __syncthreads();
    if (tid < LATH) {
      float acc = lb2[tid];
      for (int k = 0; k < LATH; ++k) acc += hbuf[k] * lW2[k * LATH + tid];
      acc = (acc - lm2[tid]) * lg2[tid] * rsqrtf(lv2[tid] + EPSB) + lbe2[tid];
      latx[b * LATH + tid] = acc;
    }
    return;
  }
  r -= NB_PREP;
  if (r < NB_SCAN) {  // ---- scans (natoms, off, aoff) + zero page ----
    __shared__ int sh[BB];
    zerobuf[tid] = 0.f;
    int v0 = 0;
    for (int e = 0; e < NEL; ++e) v0 += comp[tid * NEL + e];
    natoms[tid] = v0;
    sh[tid] = v0;
    for (int d = 1; d < BB; d <<= 1) {
      __syncthreads();
      int v = (tid >= d) ? sh[tid - d] : 0;
      __syncthreads();
      sh[tid] += v;
    }
    __syncthreads();
    off[tid] = sh[tid] - v0;
    __syncthreads();
    int sz = 3 * ((((v0 + 15) >> 4) << 4)) * ((((v0 + 31) >> 5) << 5));
    sh[tid] = sz;
    for (int d = 1; d < BB; d <<= 1) {
      __syncthreads();
      int v = (tid >= d) ? sh[tid - d] : 0;
      __syncthreads();
      sh[tid] += v;
    }
    __syncthreads();
    aoff[tid] = sh[tid] - sz;
    return;
  }
  r -= NB_SCAN;
  if (r < NB_PHYS) {  // ---- physpe rows ----
    int e = r;
    __shared__ float ph[128];
    if (tid < 32) ph[tid] = z_emb[e * 32 + tid];
    else if (tid < 64) ph[tid] = period_t[period_idx[e] * 32 + tid - 32];
    else if (tid < 96) ph[tid] = group_t[group_idx[e] * 32 + tid - 64];
    else if (tid < 128) {
      int j = tid - 96;
      float acc = bp[j];
      for (int k = 0; k < 20; ++k) acc += props[e * 20 + k] * Wp[k * 32 + j];
      ph[tid] = acc;
    }
    __syncthreads();
    float acc = bphys[tid];
    for (int k = 0; k < 128; ++k) acc += ph[k] * Wphys[k * 256 + tid];
    physpe[e * 256 + tid] = acc;
    return;
  }
  r -= NB_PHYS;
  if (r < NB_WP1 + NB_WP2) {  // ---- W transpose to bf16 W^T ----
    const float* W;
    unsigned short* Wt;
    int NC3, bx, by;
    if (r < NB_WP1) { W = gat1_W; Wt = wt1; NC3 = 3 * C1; bx = r % 14; by = r / 14; }
    else { int r2 = r - NB_WP1; W = gat2_W; Wt = wt2; NC3 = 3 * C2; bx = r2 % 14; by = r2 / 14; }
    int k0 = bx << 5, c0 = by << 5;
    __shared__ float ts[32][33];
    int e4 = tid << 2;
    int kk = e4 >> 5, cc = e4 & 31;
    float4 v = *(const float4*)(W + (size_t)(k0 + kk) * NC3 + c0 + cc);
    ts[kk][cc] = v.x; ts[kk][cc + 1] = v.y; ts[kk][cc + 2] = v.z; ts[kk][cc + 3] = v.w;
    __syncthreads();
    int c2 = tid & 31, kg = tid >> 5;
    ushort4 u;
    u.x = f2bf(ts[kg * 4 + 0][c2]); u.y = f2bf(ts[kg * 4 + 1][c2]);
    u.z = f2bf(ts[kg * 4 + 2][c2]); u.w = f2bf(ts[kg * 4 + 3][c2]);
    *(ushort4*)(Wt + (size_t)(c0 + c2) * 448 + k0 + (kg << 2)) = u;
    return;
  }
  r -= NB_WP1 + NB_WP2;
  if (r < 2 * NB_FOLD) {  // ---- fold a_s/a_d through W ----
    const float* W; const float* as_; const float* ad_;
    float* wsv; float* wdv; int NC3, C, kb;
    if (r < NB_FOLD) { W = gat1_W; as_ = gat1_as; ad_ = gat1_ad; wsv = wsv1; wdv = wdv1; NC3 = 3 * C1; C = C1; kb = r << 2; }
    else { int r2 = r - NB_FOLD; W = gat2_W; as_ = gat2_as; ad_ = gat2_ad; wsv = wsv2; wdv = wdv2; NC3 = 3 * C2; C = C2; kb = r2 << 2; }
    int k = kb + wv;
    for (int h = 0; h < 3; ++h) {
      float ss = 0.f, sd = 0.f;
      for (int c = lane; c < C; c += 64) {
        float wvv = W[(size_t)k * NC3 + h * C + c];
        ss += wvv * as_[h * C + c];
        sd += wvv * ad_[h * C + c];
      }
      for (int o = 32; o > 0; o >>= 1) { ss += __shfl_xor(ss, o); sd += __shfl_xor(sd, o); }
      if (lane == 0) { wsv[k * 3 + h] = ss; wdv[k * 3 + h] = sd; }
    }
    return;
  }
  r -= 2 * NB_FOLD;
  {  // ---- pad-row value after layer 2 ----
    int c = (r << 2) + wv;
    float s = 0.f;
    for (int k = lane; k < C1; k += 64) {
      const float* wr = gat2_W + (size_t)k * (3 * C2) + c;
      s += gat1_b[k] * (wr[0] + wr[C2] + wr[2 * C2]);
    }
    for (int o = 32; o > 0; o >>= 1) s += __shfl_xor(s, o);
    if (lane == 0) pad2[c] = s * (1.f / 3.f) + gat2_b[c];
  }
}

// ---------------- packed node features x0 [total,448] bf16 (vectorized) ----
__global__ __launch_bounds__(256) void k_nodep(
    const int* __restrict__ z, const int* __restrict__ off, const int* __restrict__ natoms,
    const float* __restrict__ physpe, const float* __restrict__ latx,
    const float* __restrict__ sgx, unsigned short* __restrict__ x0) {
  int b = blockIdx.x;
  int n = natoms[b], ob = off[b];
  int tid = threadIdx.x;
  __shared__ int zl[NMAX];
  for (int t = tid; t < n; t += 256) zl[t] = z[b * NMAX + t];
  __syncthreads();
  int items = n * 56;
  for (int e = tid; e < items; e += 256) {
    int t = e / 56, c8 = (e - t * 56) << 3;
    int zt = zl[t];
    float v[8];
    if (c8 < 256) {
      float4 a = *(const float4*)(physpe + zt * 256 + c8);
      float4 c = *(const float4*)(physpe + zt * 256 + c8 + 4);
      v[0] = a.x; v[1] = a.y; v[2] = a.z; v[3] = a.w;
      v[4] = c.x; v[5] = c.y; v[6] = c.z; v[7] = c.w;
    } else if (c8 < 384) {
      float4 a = *(const float4*)(latx + b * LATH + c8 - 256);
      float4 c = *(const float4*)(latx + b * LATH + c8 - 252);
      v[0] = a.x; v[1] = a.y; v[2] = a.z; v[3] = a.w;
      v[4] = c.x; v[5] = c.y; v[6] = c.z; v[7] = c.w;
    } else {
      float4 a = *(const float4*)(sgx + b * SGE + c8 - 384);
      float4 c = *(const float4*)(sgx + b * SGE + c8 - 380);
      v[0] = a.x; v[1] = a.y; v[2] = a.z; v[3] = a.w;
      v[4] = c.x; v[5] = c.y; v[6] = c.z; v[7] = c.w;
    }
    unsigned short u[8];
    #pragma unroll
    for (int i = 0; i < 8; ++i) u[i] = f2bf(v[i]);
    *(uint4*)(x0 + (size_t)(ob + t) * PIN + c8) = *(uint4*)u;
  }
}

// ---------------- asrc/adst: one WAVE per row (coalesced) ----------------
__global__ __launch_bounds__(256) void k_av2(
    const unsigned short* __restrict__ x, const float* __restrict__ wsv,
    const float* __restrict__ wdv, const int* __restrict__ off,
    const int* __restrict__ natoms, float* __restrict__ asrc,
    float* __restrict__ adst, int K) {
  __shared__ float sw[C1 * 3], dw[C1 * 3];
  int tid = threadIdx.x;
  for (int e = tid; e < K * 3; e += 256) { sw[e] = wsv[e]; dw[e] = wdv[e]; }
  __syncthreads();
  int total = off[BB - 1] + natoms[BB - 1];
  int wv = tid >> 6, lane = tid & 63;
  int nk8 = K >> 3;  // 56
  int stride = gridDim.x << 2;
  for (int row = (blockIdx.x << 2) + wv; row < total; row += stride) {
    float s0 = 0.f, s1 = 0.f, s2 = 0.f, d0 = 0.f, d1 = 0.f, d2 = 0.f;
    if (lane < nk8) {
      uint4 raw = *(const uint4*)(x + (size_t)row * K + (lane << 3));
      unsigned short us[8];
      *(uint4*)us = raw;
      #pragma unroll
      for (int u = 0; u < 8; ++u) {
        float xv = bf2f(us[u]);
        int kb = ((lane << 3) + u) * 3;
        s0 += xv * sw[kb + 0]; s1 += xv * sw[kb + 1]; s2 += xv * sw[kb + 2];
        d0 += xv * dw[kb + 0]; d1 += xv * dw[kb + 1]; d2 += xv * dw[kb + 2];
      }
    }
    #pragma unroll
    for (int o = 32; o > 0; o >>= 1) {
      s0 += __shfl_xor(s0, o); s1 += __shfl_xor(s1, o); s2 += __shfl_xor(s2, o);
      d0 += __shfl_xor(d0, o); d1 += __shfl_xor(d1, o); d2 += __shfl_xor(d2, o);
    }
    if (lane == 0) {
      asrc[row * 3 + 0] = s0; asrc[row * 3 + 1] = s1; asrc[row * 3 + 2] = s2;
      adst[row * 3 + 0] = d0; adst[row * 3 + 1] = d1; adst[row * 3 + 2] = d2;
    }
  }
}

// ---------------- alpha materialization (sharded): one (b,h,mtile)/block ---
#define MTMAX 17
__global__ __launch_bounds__(256) void k_alpha(
    const float* __restrict__ asrc, const float* __restrict__ adst,
    const int* __restrict__ off, const int* __restrict__ natoms,
    const int* __restrict__ aoff, unsigned short* __restrict__ alpha) {
  int bid = blockIdx.x;
  int b = bid & (BB - 1);
  int hm = bid >> 8;
  int h = hm % 3;
  int mt = hm / 3;
  int n = natoms[b];
  if (n == 0) return;
  int mtn = (n + 15) >> 4;
  if (mt >= mtn) return;
  int ktn = (n + 31) >> 5;
  int rext = mtn << 4, kext = ktn << 5;
  int ob = off[b];
  size_t ab = (size_t)aoff[b] + (size_t)h * rext * kext;
  int tid = threadIdx.x;
  int wv = tid >> 6, lane = tid & 63;
  __shared__ float asl[288];
  for (int j = tid; j < kext; j += 256)
    asl[j] = (j < n) ? asrc[(ob + j) * 3 + h] : 0.f;
  __syncthreads();
  #pragma unroll
  for (int r = 0; r < 4; ++r) {
    int i = (mt << 4) + (wv << 2) + r;
    unsigned short* rowp = alpha + ab + (size_t)i * kext;
    if (i >= n) {
      for (int j = lane; j < kext; j += 64) rowp[j] = 0;
      continue;
    }
    float ad = adst[(ob + i) * 3 + h];
    float m = -1e30f;
    for (int j = lane; j < n; j += 64) {
      float sc = asl[j] + ad;
      sc = fmaxf(sc, 0.2f * sc);
      m = fmaxf(m, sc);
    }
    for (int o = 32; o > 0; o >>= 1) m = fmaxf(m, __shfl_xor(m, o));
    float s = 0.f;
    for (int j = lane; j < n; j += 64) {
      float sc = asl[j] + ad;
      sc = fmaxf(sc, 0.2f * sc);
      s += __expf(sc - m);
    }
    for (int o = 32; o > 0; o >>= 1) s += __shfl_xor(s, o);
    float rs = 1.f / s;
    for (int j = lane; j < kext; j += 64) {
      float v = 0.f;
      if (j < n) {
        float sc = asl[j] + ad;
        sc = fmaxf(sc, 0.2f * sc);
        v = __expf(sc - m) * rs;
      }
      rowp[j] = f2bf(v);
    }
  }
}

// ---------------- fused MFMA GAT layer (64-col, async gld + dbuf LDS) ------
// LDS overlay for 3 blocks/CU (54272 B total):
//   xs0: own array, 17408 B (x tile buffer 0)
//   tt:  36864 B; during phase 1 its first 8192 B hold the W dbuf, and
//        bytes [8192, 25600) hold x tile buffer 1 (safe: t^T writes happen
//        only after the K-loop's final barrier; next head's preload happens
//        after phase-2's closing barrier).
#define MTW 5

__global__ __launch_bounds__(256, 3) void k_fused_mfma(
    const unsigned short* __restrict__ xin, const unsigned short* __restrict__ Wt,
    const unsigned short* __restrict__ alpha, const int* __restrict__ aoff,
    const int* __restrict__ off, const int* __restrict__ natoms,
    const float* __restrict__ bias, const float* __restrict__ zerobuf,
    unsigned short* __restrict__ xout, int K, int C, int NC) {
  int bid = blockIdx.x;
  int xg = bid & 7;
  int g = bid >> 3;
  int cblk = g % NC;
  int b = xg + ((g / NC) << 3);
  int c0 = cblk << 6;
  int n = natoms[b];
  if (n == 0) return;
  int ob = off[b];
  size_t ab = (size_t)aoff[b];
  int tid = threadIdx.x;
  int wv = tid >> 6;
  int lane = tid & 63;
  int m16 = lane & 15;
  int q = lane >> 4;

  int mtn = (n + 15) >> 4;
  int jmax = mtn << 4;
  int ktn = (n + 31) >> 5;
  int kext = ktn << 5;
  size_t hstride = (size_t)jmax * kext;

  __shared__ unsigned short xs0[17 * 512];  // 17408 B
  __shared__ unsigned short tt[36 * 512];   // 36864 B (wt dbuf + xs1 overlay in phase 1)
  // xs buffer 1 overlays tt at element offset 4096 (byte 8192)

  const unsigned short* xsrc[MTW];
  #pragma unroll
  for (int t_i = 0; t_i < MTW; ++t_i) {
    int mt = wv + (t_i << 2);
    int j = (mt << 4) + m16;
    xsrc[t_i] = (j < n) ? (xin + (size_t)(ob + j) * K + (q << 3))
                        : (const unsigned short*)zerobuf;
  }

  floatx4 acc[MTW][4];
  #pragma unroll
  for (int i = 0; i < MTW; ++i)
    #pragma unroll
    for (int nt = 0; nt < 4; ++nt) acc[i][nt] = (floatx4)0.f;

  for (int h = 0; h < 3; ++h) {
    floatx4 tac[MTW][4];
    #pragma unroll
    for (int i = 0; i < MTW; ++i)
      #pragma unroll
      for (int nt = 0; nt < 4; ++nt) tac[i][nt] = (floatx4)0.f;

    const unsigned short* wsrc = Wt + (size_t)(h * C + c0 + lane) * K + (wv << 3);

    #pragma unroll
    for (int t_i = 0; t_i < MTW; ++t_i) {
      int mt = wv + (t_i << 2);
      if (mt < mtn) gld16(xsrc[t_i], &xs0[mt << 9]);
    }
    gld16(wsrc, &tt[wv << 9]);
    __syncthreads();

    int buf = 0;
    for (int k0 = 0; k0 < K; k0 += 32) {
      int k1 = k0 + 32;
      if (k1 < K) {
        unsigned short* xnext = (buf == 0) ? (tt + 4096) : xs0;
        #pragma unroll
        for (int t_i = 0; t_i < MTW; ++t_i) {
          int mt = wv + (t_i << 2);
          if (mt < mtn) gld16(xsrc[t_i] + k1, xnext + (mt << 9));
        }
        gld16(wsrc + k1, &tt[((buf ^ 1) << 11) + (wv << 9)]);
      }
      const unsigned short* wb = &tt[buf << 11];
      const unsigned short* xb = (buf == 0) ? xs0 : (tt + 4096);
      shortx8 bfr[4];
      #pragma unroll
      for (int nt = 0; nt < 4; ++nt)
        bfr[nt] = *(const shortx8*)(wb + (q << 9) + (((nt << 4) + m16) << 3));
      #pragma unroll
      for (int t_i = 0; t_i < MTW; ++t_i) {
        int mt = wv + (t_i << 2);
        if (mt < mtn) {
          shortx8 a = *(const shortx8*)(xb + (mt << 9) + (((q << 4) + m16) << 3));
          #pragma unroll
          for (int nt = 0; nt < 4; ++nt)
            tac[t_i][nt] = __builtin_amdgcn_mfma_f32_16x16x32_bf16(a, bfr[nt], tac[t_i][nt], 0, 0, 0);
        }
      }
      __syncthreads();
      buf ^= 1;
    }
    #pragma unroll
    for (int t_i = 0; t_i < MTW; ++t_i) {
      int mt = wv + (t_i << 2);
      if (mt < mtn) {
        int jbase = (mt << 4) + (q << 2);
        #pragma unroll
        for (int nt = 0; nt < 4; ++nt) {
          floatx4 d = tac[t_i][nt];
          ushort4 u;
          u.x = f2bf(d.x); u.y = f2bf(d.y); u.z = f2bf(d.z); u.w = f2bf(d.w);
          int c = (nt << 4) + m16;
          *(ushort4*)(tt + ((jbase >> 3) << 9) + (c << 3) + (jbase & 7)) = u;
        }
      }
    }
    for (int e = tid; e < ((kext - jmax) << 6); e += 256) {
      int j = jmax + (e >> 6), c = e & 63;
      tt[((j >> 3) << 9) + (c << 3) + (j & 7)] = 0;
    }
    __syncthreads();
    const unsigned short* ap = alpha + ab + (size_t)h * hstride;
    for (int k0p = 0; k0p < kext; k0p += 32) {
      shortx8 tb[4];
      #pragma unroll
      for (int nt = 0; nt < 4; ++nt)
        tb[nt] = *(const shortx8*)(tt + (((k0p >> 3) + q) << 9) + (((nt << 4) + m16) << 3));
      #pragma unroll
      for (int t_i = 0; t_i < MTW; ++t_i) {
        int mt = wv + (t_i << 2);
        if (mt < mtn) {
          shortx8 af = *(const shortx8*)(ap + (size_t)((mt << 4) + m16) * kext + k0p + (q << 3));
          #pragma unroll
          for (int nt = 0; nt < 4; ++nt)
            acc[t_i][nt] = __builtin_amdgcn_mfma_f32_16x16x32_bf16(af, tb[nt], acc[t_i][nt], 0, 0, 0);
        }
      }
    }
    __syncthreads();
  }
  float bq[4];
  #pragma unroll
  for (int nt = 0; nt < 4; ++nt) bq[nt] = bias[c0 + (nt << 4) + m16];
  const float inv3 = 1.f / 3.f;
  #pragma unroll
  for (int t_i = 0; t_i < MTW; ++t_i) {
    int mt = wv + (t_i << 2);
    if (mt < mtn) {
      #pragma unroll
      for (int nt = 0; nt < 4; ++nt) {
        floatx4 d = acc[t_i][nt];
        int cidx = c0 + (nt << 4) + m16;
        #pragma unroll
        for (int r = 0; r < 4; ++r) {
          int i = (mt << 4) + (q << 2) + r;
          if (i < n) xout[(size_t)(ob + i) * C + cidx] = f2bf(d[r] * inv3 + bq[nt]);
        }
      }
    }
  }
}

// ===== merged readout + head MLP: block/graph, 512 threads =================
__global__ __launch_bounds__(512) void k_feat_head(
    const unsigned short* __restrict__ x2, const float* __restrict__ pad2,
    const int* __restrict__ off, const int* __restrict__ natoms,
    const float* __restrict__ sgx, const float* __restrict__ latx,
    const float* __restrict__ W1, const float* __restrict__ b1,
    const float* __restrict__ g1, const float* __restrict__ be1,
    const float* __restrict__ m1, const float* __restrict__ v1,
    const float* __restrict__ W2, const float* __restrict__ b2,
    const float* __restrict__ g2, const float* __restrict__ be2,
    const float* __restrict__ m2, const float* __restrict__ v2,
    const float* __restrict__ W3, const float* __restrict__ b3,
    float* __restrict__ out) {
  int b = blockIdx.x, tid = threadIdx.x;  // 512
  int wv8 = tid >> 6, lane = tid & 63;
  int n = natoms[b], ob = off[b];
  __shared__ float part[8][256];
  __shared__ float f[PIN];
  __shared__ float h1[P1];
  __shared__ float h2[P1];
  __shared__ float red[512];
  float a0 = 0.f, a1 = 0.f, a2 = 0.f, a3 = 0.f;
  for (int r = wv8; r < n; r += 8) {
    uint2 raw = *(const uint2*)(x2 + (size_t)(ob + r) * C2 + (lane << 2));
    unsigned short us[4];
    *(uint2*)us = raw;
    a0 += bf2f(us[0]); a1 += bf2f(us[1]); a2 += bf2f(us[2]); a3 += bf2f(us[3]);
  }
  {
    float4 p = make_float4(a0, a1, a2, a3);
    *(float4*)&part[wv8][lane << 2] = p;
  }
  __syncthreads();
  if (tid < 256) {
    float s = 0.f;
    #pragma unroll
    for (int w = 0; w < 8; ++w) s += part[w][tid];
    f[tid] = s + (float)(NMAX - n) * pad2[tid];
  } else if (tid < 320) {
    f[tid] = sgx[b * SGE + (tid - 256)];
  } else if (tid < 448) {
    f[tid] = latx[b * LATH + (tid - 320)];
  }
  __syncthreads();
  {
    int o = tid;
    float acc = b1[o];
    for (int k = 0; k < PIN; ++k) acc += f[k] * W1[k * P1 + o];
    acc = (acc - m1[o]) * g1[o] * rsqrtf(v1[o] + EPSB) + be1[o];
    h1[o] = acc >= 0.f ? acc : 0.2f * acc;
  }
  __syncthreads();
  {
    int o = tid;
    float acc = b2[o];
    for (int k = 0; k < P1; ++k) acc += h1[k] * W2[k * P1 + o];
    acc = (acc - m2[o]) * g2[o] * rsqrtf(v2[o] + EPSB) + be2[o];
    h2[o] = acc >= 0.f ? acc : 0.2f * acc;
  }
  __syncthreads();
  red[tid] = h2[tid] * W3[tid];
  __syncthreads();
  for (int s = 256; s > 0; s >>= 1) {
    if (tid < s) red[tid] += red[tid + s];
    __syncthreads();
  }
  if (tid == 0) out[b] = red[0] + b3[0];
}

extern "C" void kernel_launch(void* const* d_in, const int* in_sizes, int n_in,
                              void* d_out, int out_size, void* d_ws, size_t ws_size,
                              hipStream_t stream) {
  const int*   comp       = (const int*)d_in[0];
  const int*   sg         = (const int*)d_in[1];
  const float* lat        = (const float*)d_in[2];
  const int*   period_idx = (const int*)d_in[3];
  const int*   group_idx  = (const int*)d_in[4];
  const float* sg_emb     = (const float*)d_in[5];
  const float* lat_W1     = (const float*)d_in[6];
  const float* lat_b1     = (const float*)d_in[7];
  const float* lat_bn1_g  = (const float*)d_in[8];
  const float* lat_bn1_b  = (const float*)d_in[9];
  const float* lat_bn1_m  = (const float*)d_in[10];
  const float* lat_bn1_v  = (const float*)d_in[11];
  const float* lat_W2     = (const float*)d_in[12];
  const float* lat_b2     = (const float*)d_in[13];
  const float* lat_bn2_g  = (const float*)d_in[14];
  const float* lat_bn2_b  = (const float*)d_in[15];
  const float* lat_bn2_m  = (const float*)d_in[16];
  const float* lat_bn2_v  = (const float*)d_in[17];
  const float* z_emb      = (const float*)d_in[18];
  const float* period_t   = (const float*)d_in[19];
  const float* group_t    = (const float*)d_in[20];
  const float* props      = (const float*)d_in[21];
  const float* W_props    = (const float*)d_in[22];
  const float* b_props    = (const float*)d_in[23];
  const float* W_phys     = (const float*)d_in[24];
  const float* b_phys     = (const float*)d_in[25];
  const float* gat1_W     = (const float*)d_in[26];
  const float* gat1_as    = (const float*)d_in[27];
  const float* gat1_ad    = (const float*)d_in[28];
  const float* gat1_b     = (const float*)d_in[29];
  const float* gat2_W     = (const float*)d_in[30];
  const float* gat2_as    = (const float*)d_in[31];
  const float* gat2_ad    = (const float*)d_in[32];
  const float* gat2_b     = (const float*)d_in[33];
  const float* pW1        = (const float*)d_in[34];
  const float* pb1        = (const float*)d_in[35];
  const float* pbn1_g     = (const float*)d_in[36];
  const float* pbn1_b     = (const float*)d_in[37];
  const float* pbn1_m     = (const float*)d_in[38];
  const float* pbn1_v     = (const float*)d_in[39];
  const float* pW2        = (const float*)d_in[40];
  const float* pb2        = (const float*)d_in[41];
  const float* pbn2_g     = (const float*)d_in[42];
  const float* pbn2_b     = (const float*)d_in[43];
  const float* pbn2_m     = (const float*)d_in[44];
  const float* pbn2_v     = (const float*)d_in[45];
  const float* pW3        = (const float*)d_in[46];
  const float* pb3        = (const float*)d_in[47];

  float* ws = (float*)d_ws;
  const size_t o_sgx  = 0;
  const size_t o_latx = o_sgx  + (size_t)BB * SGE;
  const size_t o_nat  = o_latx + (size_t)BB * LATH;
  const size_t o_off  = o_nat  + BB;
  const size_t o_aoff = o_off  + BB;
  const size_t o_z    = o_aoff + BB;
  const size_t o_phys = o_z    + (size_t)BB * NMAX;
  const size_t o_wsv1 = o_phys + (size_t)NEL * 256;
  const size_t o_wdv1 = o_wsv1 + (size_t)C1 * 3;
  const size_t o_wsv2 = o_wdv1 + (size_t)C1 * 3;
  const size_t o_wdv2 = o_wsv2 + (size_t)C1 * 3;
  const size_t o_asrc = o_wdv2 + (size_t)C1 * 3;
  const size_t o_adst = o_asrc + (size_t)BB * NMAX * 3;
  const size_t o_pad2 = o_adst + (size_t)BB * NMAX * 3;
  const size_t o_zero = o_pad2 + 256;
  const size_t o_wt1  = o_zero + 256;
  const size_t o_wt2  = o_wt1  + (size_t)(3 * C1) * PIN / 2;
  const size_t o_x0   = o_wt2  + (size_t)(3 * C2) * C1 / 2;
  const size_t o_x1   = o_x0   + (size_t)BB * NMAX * PIN / 2;
  const size_t o_alph = o_x1   + (size_t)BB * NMAX * PIN / 2;

  float* sgx    = ws + o_sgx;
  float* latx   = ws + o_latx;
  int*   natoms = (int*)(ws + o_nat);
  int*   off    = (int*)(ws + o_off);
  int*   aoff   = (int*)(ws + o_aoff);
  int*   z      = (int*)(ws + o_z);
  float* physpe = ws + o_phys;
  float* wsv1   = ws + o_wsv1;
  float* wdv1   = ws + o_wdv1;
  float* wsv2   = ws + o_wsv2;
  float* wdv2   = ws + o_wdv2;
  float* asrc   = ws + o_asrc;
  float* adst   = ws + o_adst;
  float* pad2   = ws + o_pad2;
  float* zerobuf = ws + o_zero;
  unsigned short* wt1   = (unsigned short*)(ws + o_wt1);
  unsigned short* wt2   = (unsigned short*)(ws + o_wt2);
  unsigned short* x0    = (unsigned short*)(ws + o_x0);
  unsigned short* x1    = (unsigned short*)(ws + o_x1);
  unsigned short* x2    = x0;
  unsigned short* alpha = (unsigned short*)(ws + o_alph);

  const int ALG = BB * 3 * MTMAX;

  k_setup<<<SETUP_GRID, 256, 0, stream>>>(
      comp, sg, lat, sg_emb,
      lat_W1, lat_b1, lat_bn1_g, lat_bn1_b, lat_bn1_m, lat_bn1_v,
      lat_W2, lat_b2, lat_bn2_g, lat_bn2_b, lat_bn2_m, lat_bn2_v,
      period_idx, group_idx, z_emb, period_t, group_t, props,
      W_props, b_props, W_phys, b_phys,
      gat1_W, gat1_as, gat1_ad, gat1_b,
      gat2_W, gat2_as, gat2_ad, gat2_b,
      sgx, latx, z, natoms, off, aoff, zerobuf, physpe,
      wt1, wt2, wsv1, wdv1, wsv2, wdv2, pad2);

  k_nodep<<<BB, 256, 0, stream>>>(z, off, natoms, physpe, latx, sgx, x0);

  // ---- GAT layer 1 ----
  k_av2<<<1024, 256, 0, stream>>>(x0, wsv1, wdv1, off, natoms, asrc, adst, PIN);
  k_alpha<<<ALG, 256, 0, stream>>>(asrc, adst, off, natoms, aoff, alpha);
  k_fused_mfma<<<(C1 / 64) * BB, 256, 0, stream>>>(x0, wt1, alpha, aoff,
      off, natoms, gat1_b, zerobuf, x1, PIN, C1, C1 / 64);

  // ---- GAT layer 2 ----
  k_av2<<<1024, 256, 0, stream>>>(x1, wsv2, wdv2, off, natoms, asrc, adst, C1);
  k_alpha<<<ALG, 256, 0, stream>>>(asrc, adst, off, natoms, aoff, alpha);
  k_fused_mfma<<<(C2 / 64) * BB, 256, 0, stream>>>(x1, wt2, alpha, aoff,
      off, natoms, gat2_b, zerobuf, x2, C1, C2, C2 / 64);

  // ---- merged readout + head ----
  k_feat_head<<<BB, 512, 0, stream>>>(x2, pad2, off, natoms, sgx, latx,
      pW1, pb1, pbn1_g, pbn1_b, pbn1_m, pbn1_v,
      pW2, pb2, pbn2_g, pbn2_b, pbn2_m, pbn2_v,
      pW3, pb3, (float*)d_out);
}

// Round 16
// 734.875 us; speedup vs baseline: 1.2592x; 1.2592x over previous
//
#include <hip/hip_runtime.h>
#include <math.h>

#define BB 256
#define NEL 90
#define NMAX 270
#define C1 448
#define C2 256
#define PIN 448
#define LATH 128
#define SGE 64
#define P1 512
#define EPSB 1e-5f

typedef short shortx8 __attribute__((ext_vector_type(8)));
typedef float floatx4 __attribute__((ext_vector_type(4)));

__device__ __forceinline__ float bf2f(unsigned short u) {
  return __uint_as_float(((unsigned)u) << 16);
}
__device__ __forceinline__ unsigned short f2bf(float f) {
  unsigned x = __float_as_uint(f);
  unsigned r = (x + 0x7fffu + ((x >> 16) & 1u)) >> 16;
  return (unsigned short)r;
}
// async 16B global->LDS (gfx950). LDS dest: wave-uniform base + lane*16.
__device__ __forceinline__ void gld16(const void* g, void* l) {
  __builtin_amdgcn_global_load_lds(
      (const __attribute__((address_space(1))) unsigned int*)g,
      (__attribute__((address_space(3))) unsigned int*)l, 16, 0, 0);
}

// ================= mega prologue: prep | scan | physpe | wprep x2 | fold x2 | pad
#define NB_PREP  BB
#define NB_SCAN  1
#define NB_PHYS  NEL
#define NB_WP1   (14 * 42)
#define NB_WP2   (14 * 24)
#define NB_FOLD  112
#define NB_PAD   64
#define SETUP_GRID (NB_PREP + NB_SCAN + NB_PHYS + NB_WP1 + NB_WP2 + 2 * NB_FOLD + NB_PAD)

__global__ __launch_bounds__(256) void k_setup(
    const int* __restrict__ comp, const int* __restrict__ sg, const float* __restrict__ lat,
    const float* __restrict__ sg_emb,
    const float* __restrict__ lW1, const float* __restrict__ lb1,
    const float* __restrict__ lg1, const float* __restrict__ lbe1,
    const float* __restrict__ lm1, const float* __restrict__ lv1,
    const float* __restrict__ lW2, const float* __restrict__ lb2,
    const float* __restrict__ lg2, const float* __restrict__ lbe2,
    const float* __restrict__ lm2, const float* __restrict__ lv2,
    const int* __restrict__ period_idx, const int* __restrict__ group_idx,
    const float* __restrict__ z_emb, const float* __restrict__ period_t,
    const float* __restrict__ group_t, const float* __restrict__ props,
    const float* __restrict__ Wp, const float* __restrict__ bp,
    const float* __restrict__ Wphys, const float* __restrict__ bphys,
    const float* __restrict__ gat1_W, const float* __restrict__ gat1_as,
    const float* __restrict__ gat1_ad, const float* __restrict__ gat1_b,
    const float* __restrict__ gat2_W, const float* __restrict__ gat2_as,
    const float* __restrict__ gat2_ad, const float* __restrict__ gat2_b,
    float* __restrict__ sgx, float* __restrict__ latx, int* __restrict__ z,
    int* __restrict__ natoms, int* __restrict__ off, int* __restrict__ aoff,
    float* __restrict__ zerobuf, float* __restrict__ physpe,
    unsigned short* __restrict__ wt1, unsigned short* __restrict__ wt2,
    float* __restrict__ wsv1, float* __restrict__ wdv1,
    float* __restrict__ wsv2, float* __restrict__ wdv2, float* __restrict__ pad2) {
  int r = blockIdx.x;
  int tid = threadIdx.x;
  int wv = tid >> 6, lane = tid & 63;

  if (r < NB_PREP) {  // ---- prep (z, sgx, latx) ----
    int b = r;
    __shared__ int cum[NEL];
    __shared__ float hbuf[LATH];
    __shared__ float latl[6];
    if (tid == 0) {
      int s = 0;
      for (int e = 0; e < NEL; ++e) { s += comp[b * NEL + e]; cum[e] = s; }
    }
    if (tid < 6) latl[tid] = lat[b * 6 + tid];
    __syncthreads();
    int n = cum[NEL - 1];
    for (int t = tid; t < NMAX; t += 256) {
      int zz = -1;
      if (t < n) {
        for (int e = 0; e < NEL; ++e) { if (cum[e] > t) { zz = e; break; } }
      }
      z[b * NMAX + t] = zz;
    }
    if (tid < SGE) sgx[b * SGE + tid] = sg_emb[sg[b] * SGE + tid];
    if (tid < LATH) {
      float acc = lb1[tid];
      for (int k = 0; k < 6; ++k) acc += latl[k] * lW1[k * LATH + tid];
      acc = (acc - lm1[tid]) * lg1[tid] * rsqrtf(lv1[tid] + EPSB) + lbe1[tid];
      hbuf[tid] = acc;
    }
    __syncthreads();
    if (tid < LATH) {
      float acc = lb2[tid];
      for (int k = 0; k < LATH; ++k) acc += hbuf[k] * lW2[k * LATH + tid];
      acc = (acc - lm2[tid]) * lg2[tid] * rsqrtf(lv2[tid] + EPSB) + lbe2[tid];
      latx[b * LATH + tid] = acc;
    }
    return;
  }
  r -= NB_PREP;
  if (r < NB_SCAN) {  // ---- scans (natoms, off, aoff) + zero page ----
    __shared__ int sh[BB];
    zerobuf[tid] = 0.f;
    int v0 = 0;
    for (int e = 0; e < NEL; ++e) v0 += comp[tid * NEL + e];
    natoms[tid] = v0;
    sh[tid] = v0;
    for (int d = 1; d < BB; d <<= 1) {
      __syncthreads();
      int v = (tid >= d) ? sh[tid - d] : 0;
      __syncthreads();
      sh[tid] += v;
    }
    __syncthreads();
    off[tid] = sh[tid] - v0;
    __syncthreads();
    int sz = 3 * ((((v0 + 15) >> 4) << 4)) * ((((v0 + 31) >> 5) << 5));
    sh[tid] = sz;
    for (int d = 1; d < BB; d <<= 1) {
      __syncthreads();
      int v = (tid >= d) ? sh[tid - d] : 0;
      __syncthreads();
      sh[tid] += v;
    }
    __syncthreads();
    aoff[tid] = sh[tid] - sz;
    return;
  }
  r -= NB_SCAN;
  if (r < NB_PHYS) {  // ---- physpe rows ----
    int e = r;
    __shared__ float ph[128];
    if (tid < 32) ph[tid] = z_emb[e * 32 + tid];
    else if (tid < 64) ph[tid] = period_t[period_idx[e] * 32 + tid - 32];
    else if (tid < 96) ph[tid] = group_t[group_idx[e] * 32 + tid - 64];
    else if (tid < 128) {
      int j = tid - 96;
      float acc = bp[j];
      for (int k = 0; k < 20; ++k) acc += props[e * 20 + k] * Wp[k * 32 + j];
      ph[tid] = acc;
    }
    __syncthreads();
    float acc = bphys[tid];
    for (int k = 0; k < 128; ++k) acc += ph[k] * Wphys[k * 256 + tid];
    physpe[e * 256 + tid] = acc;
    return;
  }
  r -= NB_PHYS;
  if (r < NB_WP1 + NB_WP2) {  // ---- W transpose to bf16 W^T ----
    const float* W;
    unsigned short* Wt;
    int NC3, bx, by;
    if (r < NB_WP1) { W = gat1_W; Wt = wt1; NC3 = 3 * C1; bx = r % 14; by = r / 14; }
    else { int r2 = r - NB_WP1; W = gat2_W; Wt = wt2; NC3 = 3 * C2; bx = r2 % 14; by = r2 / 14; }
    int k0 = bx << 5, c0 = by << 5;
    __shared__ float ts[32][33];
    int e4 = tid << 2;
    int kk = e4 >> 5, cc = e4 & 31;
    float4 v = *(const float4*)(W + (size_t)(k0 + kk) * NC3 + c0 + cc);
    ts[kk][cc] = v.x; ts[kk][cc + 1] = v.y; ts[kk][cc + 2] = v.z; ts[kk][cc + 3] = v.w;
    __syncthreads();
    int c2 = tid & 31, kg = tid >> 5;
    ushort4 u;
    u.x = f2bf(ts[kg * 4 + 0][c2]); u.y = f2bf(ts[kg * 4 + 1][c2]);
    u.z = f2bf(ts[kg * 4 + 2][c2]); u.w = f2bf(ts[kg * 4 + 3][c2]);
    *(ushort4*)(Wt + (size_t)(c0 + c2) * 448 + k0 + (kg << 2)) = u;
    return;
  }
  r -= NB_WP1 + NB_WP2;
  if (r < 2 * NB_FOLD) {  // ---- fold a_s/a_d through W ----
    const float* W; const float* as_; const float* ad_;
    float* wsv; float* wdv; int NC3, C, kb;
    if (r < NB_FOLD) { W = gat1_W; as_ = gat1_as; ad_ = gat1_ad; wsv = wsv1; wdv = wdv1; NC3 = 3 * C1; C = C1; kb = r << 2; }
    else { int r2 = r - NB_FOLD; W = gat2_W; as_ = gat2_as; ad_ = gat2_ad; wsv = wsv2; wdv = wdv2; NC3 = 3 * C2; C = C2; kb = r2 << 2; }
    int k = kb + wv;
    for (int h = 0; h < 3; ++h) {
      float ss = 0.f, sd = 0.f;
      for (int c = lane; c < C; c += 64) {
        float wvv = W[(size_t)k * NC3 + h * C + c];
        ss += wvv * as_[h * C + c];
        sd += wvv * ad_[h * C + c];
      }
      for (int o = 32; o > 0; o >>= 1) { ss += __shfl_xor(ss, o); sd += __shfl_xor(sd, o); }
      if (lane == 0) { wsv[k * 3 + h] = ss; wdv[k * 3 + h] = sd; }
    }
    return;
  }
  r -= 2 * NB_FOLD;
  {  // ---- pad-row value after layer 2 ----
    int c = (r << 2) + wv;
    float s = 0.f;
    for (int k = lane; k < C1; k += 64) {
      const float* wr = gat2_W + (size_t)k * (3 * C2) + c;
      s += gat1_b[k] * (wr[0] + wr[C2] + wr[2 * C2]);
    }
    for (int o = 32; o > 0; o >>= 1) s += __shfl_xor(s, o);
    if (lane == 0) pad2[c] = s * (1.f / 3.f) + gat2_b[c];
  }
}

// ---------------- packed node features x0 [total,448] bf16 (vectorized) ----
__global__ __launch_bounds__(256) void k_nodep(
    const int* __restrict__ z, const int* __restrict__ off, const int* __restrict__ natoms,
    const float* __restrict__ physpe, const float* __restrict__ latx,
    const float* __restrict__ sgx, unsigned short* __restrict__ x0) {
  int b = blockIdx.x;
  int n = natoms[b], ob = off[b];
  int tid = threadIdx.x;
  __shared__ int zl[NMAX];
  for (int t = tid; t < n; t += 256) zl[t] = z[b * NMAX + t];
  __syncthreads();
  int items = n * 56;
  for (int e = tid; e < items; e += 256) {
    int t = e / 56, c8 = (e - t * 56) << 3;
    int zt = zl[t];
    float v[8];
    if (c8 < 256) {
      float4 a = *(const float4*)(physpe + zt * 256 + c8);
      float4 c = *(const float4*)(physpe + zt * 256 + c8 + 4);
      v[0] = a.x; v[1] = a.y; v[2] = a.z; v[3] = a.w;
      v[4] = c.x; v[5] = c.y; v[6] = c.z; v[7] = c.w;
    } else if (c8 < 384) {
      float4 a = *(const float4*)(latx + b * LATH + c8 - 256);
      float4 c = *(const float4*)(latx + b * LATH + c8 - 252);
      v[0] = a.x; v[1] = a.y; v[2] = a.z; v[3] = a.w;
      v[4] = c.x; v[5] = c.y; v[6] = c.z; v[7] = c.w;
    } else {
      float4 a = *(const float4*)(sgx + b * SGE + c8 - 384);
      float4 c = *(const float4*)(sgx + b * SGE + c8 - 380);
      v[0] = a.x; v[1] = a.y; v[2] = a.z; v[3] = a.w;
      v[4] = c.x; v[5] = c.y; v[6] = c.z; v[7] = c.w;
    }
    unsigned short u[8];
    #pragma unroll
    for (int i = 0; i < 8; ++i) u[i] = f2bf(v[i]);
    *(uint4*)(x0 + (size_t)(ob + t) * PIN + c8) = *(uint4*)u;
  }
}

// ---------------- asrc/adst: one WAVE per row (coalesced) ----------------
__global__ __launch_bounds__(256) void k_av2(
    const unsigned short* __restrict__ x, const float* __restrict__ wsv,
    const float* __restrict__ wdv, const int* __restrict__ off,
    const int* __restrict__ natoms, float* __restrict__ asrc,
    float* __restrict__ adst, int K) {
  __shared__ float sw[C1 * 3], dw[C1 * 3];
  int tid = threadIdx.x;
  for (int e = tid; e < K * 3; e += 256) { sw[e] = wsv[e]; dw[e] = wdv[e]; }
  __syncthreads();
  int total = off[BB - 1] + natoms[BB - 1];
  int wv = tid >> 6, lane = tid & 63;
  int nk8 = K >> 3;  // 56
  int stride = gridDim.x << 2;
  for (int row = (blockIdx.x << 2) + wv; row < total; row += stride) {
    float s0 = 0.f, s1 = 0.f, s2 = 0.f, d0 = 0.f, d1 = 0.f, d2 = 0.f;
    if (lane < nk8) {
      uint4 raw = *(const uint4*)(x + (size_t)row * K + (lane << 3));
      unsigned short us[8];
      *(uint4*)us = raw;
      #pragma unroll
      for (int u = 0; u < 8; ++u) {
        float xv = bf2f(us[u]);
        int kb = ((lane << 3) + u) * 3;
        s0 += xv * sw[kb + 0]; s1 += xv * sw[kb + 1]; s2 += xv * sw[kb + 2];
        d0 += xv * dw[kb + 0]; d1 += xv * dw[kb + 1]; d2 += xv * dw[kb + 2];
      }
    }
    #pragma unroll
    for (int o = 32; o > 0; o >>= 1) {
      s0 += __shfl_xor(s0, o); s1 += __shfl_xor(s1, o); s2 += __shfl_xor(s2, o);
      d0 += __shfl_xor(d0, o); d1 += __shfl_xor(d1, o); d2 += __shfl_xor(d2, o);
    }
    if (lane == 0) {
      asrc[row * 3 + 0] = s0; asrc[row * 3 + 1] = s1; asrc[row * 3 + 2] = s2;
      adst[row * 3 + 0] = d0; adst[row * 3 + 1] = d1; adst[row * 3 + 2] = d2;
    }
  }
}

// ---------------- alpha materialization (sharded): one (b,h,mtile)/block ---
#define MTMAX 17
__global__ __launch_bounds__(256) void k_alpha(
    const float* __restrict__ asrc, const float* __restrict__ adst,
    const int* __restrict__ off, const int* __restrict__ natoms,
    const int* __restrict__ aoff, unsigned short* __restrict__ alpha) {
  int bid = blockIdx.x;
  int b = bid & (BB - 1);
  int hm = bid >> 8;
  int h = hm % 3;
  int mt = hm / 3;
  int n = natoms[b];
  if (n == 0) return;
  int mtn = (n + 15) >> 4;
  if (mt >= mtn) return;
  int ktn = (n + 31) >> 5;
  int rext = mtn << 4, kext = ktn << 5;
  int ob = off[b];
  size_t ab = (size_t)aoff[b] + (size_t)h * rext * kext;
  int tid = threadIdx.x;
  int wv = tid >> 6, lane = tid & 63;
  __shared__ float asl[288];
  for (int j = tid; j < kext; j += 256)
    asl[j] = (j < n) ? asrc[(ob + j) * 3 + h] : 0.f;
  __syncthreads();
  #pragma unroll
  for (int r = 0; r < 4; ++r) {
    int i = (mt << 4) + (wv << 2) + r;
    unsigned short* rowp = alpha + ab + (size_t)i * kext;
    if (i >= n) {
      for (int j = lane; j < kext; j += 64) rowp[j] = 0;
      continue;
    }
    float ad = adst[(ob + i) * 3 + h];
    float m = -1e30f;
    for (int j = lane; j < n; j += 64) {
      float sc = asl[j] + ad;
      sc = fmaxf(sc, 0.2f * sc);
      m = fmaxf(m, sc);
    }
    for (int o = 32; o > 0; o >>= 1) m = fmaxf(m, __shfl_xor(m, o));
    float s = 0.f;
    for (int j = lane; j < n; j += 64) {
      float sc = asl[j] + ad;
      sc = fmaxf(sc, 0.2f * sc);
      s += __expf(sc - m);
    }
    for (int o = 32; o > 0; o >>= 1) s += __shfl_xor(s, o);
    float rs = 1.f / s;
    for (int j = lane; j < kext; j += 64) {
      float v = 0.f;
      if (j < n) {
        float sc = asl[j] + ad;
        sc = fmaxf(sc, 0.2f * sc);
        v = __expf(sc - m) * rs;
      }
      rowp[j] = f2bf(v);
    }
  }
}

// ---------------- fused MFMA GAT layer (64-col, async gld + dbuf LDS) ------
// LDS overlay (54272 B total -> 3 blocks/CU by LDS):
//   xs0: own array, 17408 B (x tile buffer 0)
//   tt:  36864 B; phase 1 uses first 8192 B as W dbuf and bytes [8192,25600)
//        as x tile buffer 1. launch_bounds(256,2): do NOT squeeze the VGPR
//        budget (R15 showed (256,3) forces accumulator spill to scratch).
#define MTW 5

__global__ __launch_bounds__(256, 2) void k_fused_mfma(
    const unsigned short* __restrict__ xin, const unsigned short* __restrict__ Wt,
    const unsigned short* __restrict__ alpha, const int* __restrict__ aoff,
    const int* __restrict__ off, const int* __restrict__ natoms,
    const float* __restrict__ bias, const float* __restrict__ zerobuf,
    unsigned short* __restrict__ xout, int K, int C, int NC) {
  int bid = blockIdx.x;
  int xg = bid & 7;
  int g = bid >> 3;
  int cblk = g % NC;
  int b = xg + ((g / NC) << 3);
  int c0 = cblk << 6;
  int n = natoms[b];
  if (n == 0) return;
  int ob = off[b];
  size_t ab = (size_t)aoff[b];
  int tid = threadIdx.x;
  int wv = tid >> 6;
  int lane = tid & 63;
  int m16 = lane & 15;
  int q = lane >> 4;

  int mtn = (n + 15) >> 4;
  int jmax = mtn << 4;
  int ktn = (n + 31) >> 5;
  int kext = ktn << 5;
  size_t hstride = (size_t)jmax * kext;

  __shared__ unsigned short xs0[17 * 512];  // 17408 B
  __shared__ unsigned short tt[36 * 512];   // 36864 B (wt dbuf + xs1 overlay in phase 1)

  const unsigned short* xsrc[MTW];
  #pragma unroll
  for (int t_i = 0; t_i < MTW; ++t_i) {
    int mt = wv + (t_i << 2);
    int j = (mt << 4) + m16;
    xsrc[t_i] = (j < n) ? (xin + (size_t)(ob + j) * K + (q << 3))
                        : (const unsigned short*)zerobuf;
  }

  floatx4 acc[MTW][4];
  #pragma unroll
  for (int i = 0; i < MTW; ++i)
    #pragma unroll
    for (int nt = 0; nt < 4; ++nt) acc[i][nt] = (floatx4)0.f;

  for (int h = 0; h < 3; ++h) {
    floatx4 tac[MTW][4];
    #pragma unroll
    for (int i = 0; i < MTW; ++i)
      #pragma unroll
      for (int nt = 0; nt < 4; ++nt) tac[i][nt] = (floatx4)0.f;

    const unsigned short* wsrc = Wt + (size_t)(h * C + c0 + lane) * K + (wv << 3);

    #pragma unroll
    for (int t_i = 0; t_i < MTW; ++t_i) {
      int mt = wv + (t_i << 2);
      if (mt < mtn) gld16(xsrc[t_i], &xs0[mt << 9]);
    }
    gld16(wsrc, &tt[wv << 9]);
    __syncthreads();

    int buf = 0;
    for (int k0 = 0; k0 < K; k0 += 32) {
      int k1 = k0 + 32;
      if (k1 < K) {
        unsigned short* xnext = (buf == 0) ? (tt + 4096) : xs0;
        #pragma unroll
        for (int t_i = 0; t_i < MTW; ++t_i) {
          int mt = wv + (t_i << 2);
          if (mt < mtn) gld16(xsrc[t_i] + k1, xnext + (mt << 9));
        }
        gld16(wsrc + k1, &tt[((buf ^ 1) << 11) + (wv << 9)]);
      }
      const unsigned short* wb = &tt[buf << 11];
      const unsigned short* xb = (buf == 0) ? xs0 : (tt + 4096);
      shortx8 bfr[4];
      #pragma unroll
      for (int nt = 0; nt < 4; ++nt)
        bfr[nt] = *(const shortx8*)(wb + (q << 9) + (((nt << 4) + m16) << 3));
      #pragma unroll
      for (int t_i = 0; t_i < MTW; ++t_i) {
        int mt = wv + (t_i << 2);
        if (mt < mtn) {
          shortx8 a = *(const shortx8*)(xb + (mt << 9) + (((q << 4) + m16) << 3));
          #pragma unroll
          for (int nt = 0; nt < 4; ++nt)
            tac[t_i][nt] = __builtin_amdgcn_mfma_f32_16x16x32_bf16(a, bfr[nt], tac[t_i][nt], 0, 0, 0);
        }
      }
      __syncthreads();
      buf ^= 1;
    }
    #pragma unroll
    for (int t_i = 0; t_i < MTW; ++t_i) {
      int mt = wv + (t_i << 2);
      if (mt < mtn) {
        int jbase = (mt << 4) + (q << 2);
        #pragma unroll
        for (int nt = 0; nt < 4; ++nt) {
          floatx4 d = tac[t_i][nt];
          ushort4 u;
          u.x = f2bf(d.x); u.y = f2bf(d.y); u.z = f2bf(d.z); u.w = f2bf(d.w);
          int c = (nt << 4) + m16;
          *(ushort4*)(tt + ((jbase >> 3) << 9) + (c << 3) + (jbase & 7)) = u;
        }
      }
    }
    for (int e = tid; e < ((kext - jmax) << 6); e += 256) {
      int j = jmax + (e >> 6), c = e & 63;
      tt[((j >> 3) << 9) + (c << 3) + (j & 7)] = 0;
    }
    __syncthreads();
    const unsigned short* ap = alpha + ab + (size_t)h * hstride;
    for (int k0p = 0; k0p < kext; k0p += 32) {
      shortx8 tb[4];
      #pragma unroll
      for (int nt = 0; nt < 4; ++nt)
        tb[nt] = *(const shortx8*)(tt + (((k0p >> 3) + q) << 9) + (((nt << 4) + m16) << 3));
      #pragma unroll
      for (int t_i = 0; t_i < MTW; ++t_i) {
        int mt = wv + (t_i << 2);
        if (mt < mtn) {
          shortx8 af = *(const shortx8*)(ap + (size_t)((mt << 4) + m16) * kext + k0p + (q << 3));
          #pragma unroll
          for (int nt = 0; nt < 4; ++nt)
            acc[t_i][nt] = __builtin_amdgcn_mfma_f32_16x16x32_bf16(af, tb[nt], acc[t_i][nt], 0, 0, 0);
        }
      }
    }
    __syncthreads();
  }
  float bq[4];
  #pragma unroll
  for (int nt = 0; nt < 4; ++nt) bq[nt] = bias[c0 + (nt << 4) + m16];
  const float inv3 = 1.f / 3.f;
  #pragma unroll
  for (int t_i = 0; t_i < MTW; ++t_i) {
    int mt = wv + (t_i << 2);
    if (mt < mtn) {
      #pragma unroll
      for (int nt = 0; nt < 4; ++nt) {
        floatx4 d = acc[t_i][nt];
        int cidx = c0 + (nt << 4) + m16;
        #pragma unroll
        for (int r = 0; r < 4; ++r) {
          int i = (mt << 4) + (q << 2) + r;
          if (i < n) xout[(size_t)(ob + i) * C + cidx] = f2bf(d[r] * inv3 + bq[nt]);
        }
      }
    }
  }
}

// ===== merged readout + head MLP: block/graph, 512 threads =================
__global__ __launch_bounds__(512) void k_feat_head(
    const unsigned short* __restrict__ x2, const float* __restrict__ pad2,
    const int* __restrict__ off, const int* __restrict__ natoms,
    const float* __restrict__ sgx, const float* __restrict__ latx,
    const float* __restrict__ W1, const float* __restrict__ b1,
    const float* __restrict__ g1, const float* __restrict__ be1,
    const float* __restrict__ m1, const float* __restrict__ v1,
    const float* __restrict__ W2, const float* __restrict__ b2,
    const float* __restrict__ g2, const float* __restrict__ be2,
    const float* __restrict__ m2, const float* __restrict__ v2,
    const float* __restrict__ W3, const float* __restrict__ b3,
    float* __restrict__ out) {
  int b = blockIdx.x, tid = threadIdx.x;  // 512
  int wv8 = tid >> 6, lane = tid & 63;
  int n = natoms[b], ob = off[b];
  __shared__ float part[8][256];
  __shared__ float f[PIN];
  __shared__ float h1[P1];
  __shared__ float h2[P1];
  __shared__ float red[512];
  float a0 = 0.f, a1 = 0.f, a2 = 0.f, a3 = 0.f;
  for (int r = wv8; r < n; r += 8) {
    uint2 raw = *(const uint2*)(x2 + (size_t)(ob + r) * C2 + (lane << 2));
    unsigned short us[4];
    *(uint2*)us = raw;
    a0 += bf2f(us[0]); a1 += bf2f(us[1]); a2 += bf2f(us[2]); a3 += bf2f(us[3]);
  }
  {
    float4 p = make_float4(a0, a1, a2, a3);
    *(float4*)&part[wv8][lane << 2] = p;
  }
  __syncthreads();
  if (tid < 256) {
    float s = 0.f;
    #pragma unroll
    for (int w = 0; w < 8; ++w) s += part[w][tid];
    f[tid] = s + (float)(NMAX - n) * pad2[tid];
  } else if (tid < 320) {
    f[tid] = sgx[b * SGE + (tid - 256)];
  } else if (tid < 448) {
    f[tid] = latx[b * LATH + (tid - 320)];
  }
  __syncthreads();
  {
    int o = tid;
    float acc = b1[o];
    for (int k = 0; k < PIN; ++k) acc += f[k] * W1[k * P1 + o];
    acc = (acc - m1[o]) * g1[o] * rsqrtf(v1[o] + EPSB) + be1[o];
    h1[o] = acc >= 0.f ? acc : 0.2f * acc;
  }
  __syncthreads();
  {
    int o = tid;
    float acc = b2[o];
    for (int k = 0; k < P1; ++k) acc += h1[k] * W2[k * P1 + o];
    acc = (acc - m2[o]) * g2[o] * rsqrtf(v2[o] + EPSB) + be2[o];
    h2[o] = acc >= 0.f ? acc : 0.2f * acc;
  }
  __syncthreads();
  red[tid] = h2[tid] * W3[tid];
  __syncthreads();
  for (int s = 256; s > 0; s >>= 1) {
    if (tid < s) red[tid] += red[tid + s];
    __syncthreads();
  }
  if (tid == 0) out[b] = red[0] + b3[0];
}

extern "C" void kernel_launch(void* const* d_in, const int* in_sizes, int n_in,
                              void* d_out, int out_size, void* d_ws, size_t ws_size,
                              hipStream_t stream) {
  const int*   comp       = (const int*)d_in[0];
  const int*   sg         = (const int*)d_in[1];
  const float* lat        = (const float*)d_in[2];
  const int*   period_idx = (const int*)d_in[3];
  const int*   group_idx  = (const int*)d_in[4];
  const float* sg_emb     = (const float*)d_in[5];
  const float* lat_W1     = (const float*)d_in[6];
  const float* lat_b1     = (const float*)d_in[7];
  const float* lat_bn1_g  = (const float*)d_in[8];
  const float* lat_bn1_b  = (const float*)d_in[9];
  const float* lat_bn1_m  = (const float*)d_in[10];
  const float* lat_bn1_v  = (const float*)d_in[11];
  const float* lat_W2     = (const float*)d_in[12];
  const float* lat_b2     = (const float*)d_in[13];
  const float* lat_bn2_g  = (const float*)d_in[14];
  const float* lat_bn2_b  = (const float*)d_in[15];
  const float* lat_bn2_m  = (const float*)d_in[16];
  const float* lat_bn2_v  = (const float*)d_in[17];
  const float* z_emb      = (const float*)d_in[18];
  const float* period_t   = (const float*)d_in[19];
  const float* group_t    = (const float*)d_in[20];
  const float* props      = (const float*)d_in[21];
  const float* W_props    = (const float*)d_in[22];
  const float* b_props    = (const float*)d_in[23];
  const float* W_phys     = (const float*)d_in[24];
  const float* b_phys     = (const float*)d_in[25];
  const float* gat1_W     = (const float*)d_in[26];
  const float* gat1_as    = (const float*)d_in[27];
  const float* gat1_ad    = (const float*)d_in[28];
  const float* gat1_b     = (const float*)d_in[29];
  const float* gat2_W     = (const float*)d_in[30];
  const float* gat2_as    = (const float*)d_in[31];
  const float* gat2_ad    = (const float*)d_in[32];
  const float* gat2_b     = (const float*)d_in[33];
  const float* pW1        = (const float*)d_in[34];
  const float* pb1        = (const float*)d_in[35];
  const float* pbn1_g     = (const float*)d_in[36];
  const float* pbn1_b     = (const float*)d_in[37];
  const float* pbn1_m     = (const float*)d_in[38];
  const float* pbn1_v     = (const float*)d_in[39];
  const float* pW2        = (const float*)d_in[40];
  const float* pb2        = (const float*)d_in[41];
  const float* pbn2_g     = (const float*)d_in[42];
  const float* pbn2_b     = (const float*)d_in[43];
  const float* pbn2_m     = (const float*)d_in[44];
  const float* pbn2_v     = (const float*)d_in[45];
  const float* pW3        = (const float*)d_in[46];
  const float* pb3        = (const float*)d_in[47];

  float* ws = (float*)d_ws;
  const size_t o_sgx  = 0;
  const size_t o_latx = o_sgx  + (size_t)BB * SGE;
  const size_t o_nat  = o_latx + (size_t)BB * LATH;
  const size_t o_off  = o_nat  + BB;
  const size_t o_aoff = o_off  + BB;
  const size_t o_z    = o_aoff + BB;
  const size_t o_phys = o_z    + (size_t)BB * NMAX;
  const size_t o_wsv1 = o_phys + (size_t)NEL * 256;
  const size_t o_wdv1 = o_wsv1 + (size_t)C1 * 3;
  const size_t o_wsv2 = o_wdv1 + (size_t)C1 * 3;
  const size_t o_wdv2 = o_wsv2 + (size_t)C1 * 3;
  const size_t o_asrc = o_wdv2 + (size_t)C1 * 3;
  const size_t o_adst = o_asrc + (size_t)BB * NMAX * 3;
  const size_t o_pad2 = o_adst + (size_t)BB * NMAX * 3;
  const size_t o_zero = o_pad2 + 256;
  const size_t o_wt1  = o_zero + 256;
  const size_t o_wt2  = o_wt1  + (size_t)(3 * C1) * PIN / 2;
  const size_t o_x0   = o_wt2  + (size_t)(3 * C2) * C1 / 2;
  const size_t o_x1   = o_x0   + (size_t)BB * NMAX * PIN / 2;
  const size_t o_alph = o_x1   + (size_t)BB * NMAX * PIN / 2;

  float* sgx    = ws + o_sgx;
  float* latx   = ws + o_latx;
  int*   natoms = (int*)(ws + o_nat);
  int*   off    = (int*)(ws + o_off);
  int*   aoff   = (int*)(ws + o_aoff);
  int*   z      = (int*)(ws + o_z);
  float* physpe = ws + o_phys;
  float* wsv1   = ws + o_wsv1;
  float* wdv1   = ws + o_wdv1;
  float* wsv2   = ws + o_wsv2;
  float* wdv2   = ws + o_wdv2;
  float* asrc   = ws + o_asrc;
  float* adst   = ws + o_adst;
  float* pad2   = ws + o_pad2;
  float* zerobuf = ws + o_zero;
  unsigned short* wt1   = (unsigned short*)(ws + o_wt1);
  unsigned short* wt2   = (unsigned short*)(ws + o_wt2);
  unsigned short* x0    = (unsigned short*)(ws + o_x0);
  unsigned short* x1    = (unsigned short*)(ws + o_x1);
  unsigned short* x2    = x0;
  unsigned short* alpha = (unsigned short*)(ws + o_alph);

  const int ALG = BB * 3 * MTMAX;

  k_setup<<<SETUP_GRID, 256, 0, stream>>>(
      comp, sg, lat, sg_emb,
      lat_W1, lat_b1, lat_bn1_g, lat_bn1_b, lat_bn1_m, lat_bn1_v,
      lat_W2, lat_b2, lat_bn2_g, lat_bn2_b, lat_bn2_m, lat_bn2_v,
      period_idx, group_idx, z_emb, period_t, group_t, props,
      W_props, b_props, W_phys, b_phys,
      gat1_W, gat1_as, gat1_ad, gat1_b,
      gat2_W, gat2_as, gat2_ad, gat2_b,
      sgx, latx, z, natoms, off, aoff, zerobuf, physpe,
      wt1, wt2, wsv1, wdv1, wsv2, wdv2, pad2);

  k_nodep<<<BB, 256, 0, stream>>>(z, off, natoms, physpe, latx, sgx, x0);

  // ---- GAT layer 1 ----
  k_av2<<<1024, 256, 0, stream>>>(x0, wsv1, wdv1, off, natoms, asrc, adst, PIN);
  k_alpha<<<ALG, 256, 0, stream>>>(asrc, adst, off, natoms, aoff, alpha);
  k_fused_mfma<<<(C1 / 64) * BB, 256, 0, stream>>>(x0, wt1, alpha, aoff,
      off, natoms, gat1_b, zerobuf, x1, PIN, C1, C1 / 64);

  // ---- GAT layer 2 ----
  k_av2<<<1024, 256, 0, stream>>>(x1, wsv2, wdv2, off, natoms, asrc, adst, C1);
  k_alpha<<<ALG, 256, 0, stream>>>(asrc, adst, off, natoms, aoff, alpha);
  k_fused_mfma<<<(C2 / 64) * BB, 256, 0, stream>>>(x1, wt2, alpha, aoff,
      off, natoms, gat2_b, zerobuf, x2, C1, C2, C2 / 64);

  // ---- merged readout + head ----
  k_feat_head<<<BB, 512, 0, stream>>>(x2, pad2, off, natoms, sgx, latx,
      pW1, pb1, pbn1_g, pbn1_b, pbn1_m, pbn1_v,
      pW2, pb2, pbn2_g, pbn2_b, pbn2_m, pbn2_v,
      pW3, pb3, (float*)d_out);
}